// Round 13
// baseline (1645.609 us; speedup 1.0000x reference)
//
#include <hip/hip_runtime.h>
#include <hip/hip_bf16.h>
#include <math.h>

#define BB 64
#define TT 32
#define HH 512
#define H2 1024
#define H4 2048
#define SS 400

// ---- workspace layout (float offsets) ----
#define OFF_WT_HI 0u          // WT hi: [2048 n][1536 k] bf16 = 1572864 floats
#define OFF_WT_LO 1572864u
#define OFF_WIT_HI 3145728u   // W_inT hi: [512 n][512 k] bf16 = 131072 floats
#define OFF_WIT_LO 3276800u
#define OFF_EH    3407872u    // E hi: [32][64][512] bf16
#define OFF_EL    3932160u
#define OFF_OH    4456448u    // O planes [64][512] bf16
#define OFF_OL    4472832u
#define OFF_HHP   4489216u    // (fallback) h planes [128][512] bf16
#define OFF_HLP   4521984u
#define OFF_TC    4554752u    // fp32 [2 slot][64][512]
#define OFF_XC    4620288u
#define OFF_TH    4685824u    // (fallback)
#define OFF_XH    4751360u
#define OFF_G     4816896u    // fallback gpart; fast: hhp2/hlp2 [2][128][512] bf16
#define OFF_HHP2  OFF_G
#define OFF_HLP2  (OFF_G + 65536u)
#define OFF_TGTP  6914048u    // tgt FINAL [128][512] fp32
#define OFF_PACC  7438336u    // [1024 pidx][512]
#define OFF_PML   7962624u    // [1024][2]
#define OFF_CTX16 7964672u    // bf16 ctx [2][64][400][512]
#define WS_NEED_F 21071872u
#define OFF_WOT_HI 21071872u  // W_outT hi: [512 n][2048 k] bf16
#define OFF_WOT_LO 21596160u
#define OFF_COMBH  22120448u  // comb hi: [64][1024] bf16
#define OFF_COMBL  22153216u
#define WS_NEED2_F 22185984u
#define OFF_PART  OFF_G       // fallback k_outB partials alias consumed G

typedef short bf16x8 __attribute__((ext_vector_type(8)));
typedef float f32x4  __attribute__((ext_vector_type(4)));

__device__ __forceinline__ float sigm(float x){ return 1.f/(1.f+__expf(-x)); }

__device__ __forceinline__ unsigned short bf_rn(float x){
  unsigned int u = __float_as_uint(x);
  return (unsigned short)((u + 0x7fffu + ((u>>16)&1u)) >> 16);
}
__device__ __forceinline__ void split2(float x, unsigned short &h, unsigned short &l){
  h = bf_rn(x);
  float hf = __uint_as_float(((unsigned int)h)<<16);
  l = bf_rn(x - hf);
}
__device__ __forceinline__ float blo(unsigned int u){ return __uint_as_float(u<<16); }
__device__ __forceinline__ float bhi(unsigned int u){ return __uint_as_float(u & 0xffff0000u); }

// ---- one-time: transpose W=[Wx;Wh] (1536x2048) -> WT[n][k] hi/lo bf16 ----
__global__ __launch_bounds__(256) void k_wprep(const float* __restrict__ Wx,
    const float* __restrict__ Wh, unsigned short* __restrict__ wt_hi,
    unsigned short* __restrict__ wt_lo){
  __shared__ float lds[64][68];
  int bk = blockIdx.x >> 5, bn = blockIdx.x & 31;
  int k0 = bk*64, n0 = bn*64;
  int tid = threadIdx.x;
  #pragma unroll
  for (int i=0;i<4;i++){
    int flat = tid + i*256;
    int k = flat >> 4, nq = flat & 15;
    int kg = k0 + k;
    const float* srow = (kg < 1024) ? Wx + (size_t)kg*H4 : Wh + (size_t)(kg-1024)*H4;
    float4 v = *(const float4*)(srow + n0 + nq*4);
    *(float4*)&lds[k][nq*4] = v;
  }
  __syncthreads();
  #pragma unroll
  for (int i=0;i<2;i++){
    int flat = tid + i*256;
    int n = flat >> 3, k8 = flat & 7;
    ushort4 h0, h1, l0, l1;
    unsigned short h[8], l[8];
    #pragma unroll
    for (int j=0;j<8;j++) split2(lds[k8*8+j][n], h[j], l[j]);
    h0.x=h[0];h0.y=h[1];h0.z=h[2];h0.w=h[3]; h1.x=h[4];h1.y=h[5];h1.z=h[6];h1.w=h[7];
    l0.x=l[0];l0.y=l[1];l0.z=l[2];l0.w=l[3]; l1.x=l[4];l1.y=l[5];l1.z=l[6];l1.w=l[7];
    size_t dst = (size_t)(n0+n)*1536 + k0 + k8*8;
    *(ushort4*)(wt_hi+dst) = h0; *(ushort4*)(wt_hi+dst+4) = h1;
    *(ushort4*)(wt_lo+dst) = l0; *(ushort4*)(wt_lo+dst+4) = l1;
  }
}

// ---- one-time: transpose W_in (512x512) -> WIT[n][k] hi/lo bf16 ----
__global__ __launch_bounds__(256) void k_wiprep(const float* __restrict__ W_in,
    unsigned short* __restrict__ wit_hi, unsigned short* __restrict__ wit_lo){
  __shared__ float lds[64][68];
  int bk = blockIdx.x >> 3, bn = blockIdx.x & 7;
  int k0 = bk*64, n0 = bn*64;
  int tid = threadIdx.x;
  #pragma unroll
  for (int i=0;i<4;i++){
    int flat = tid + i*256;
    int k = flat >> 4, nq = flat & 15;
    float4 v = *(const float4*)(W_in + (size_t)(k0+k)*HH + n0 + nq*4);
    *(float4*)&lds[k][nq*4] = v;
  }
  __syncthreads();
  #pragma unroll
  for (int i=0;i<2;i++){
    int flat = tid + i*256;
    int n = flat >> 3, k8 = flat & 7;
    ushort4 h0, h1, l0, l1;
    unsigned short h[8], l[8];
    #pragma unroll
    for (int j=0;j<8;j++) split2(lds[k8*8+j][n], h[j], l[j]);
    h0.x=h[0];h0.y=h[1];h0.z=h[2];h0.w=h[3]; h1.x=h[4];h1.y=h[5];h1.z=h[6];h1.w=h[7];
    l0.x=l[0];l0.y=l[1];l0.z=l[2];l0.w=l[3]; l1.x=l[4];l1.y=l[5];l1.z=l[6];l1.w=l[7];
    size_t dst = (size_t)(n0+n)*HH + k0 + k8*8;
    *(ushort4*)(wit_hi+dst) = h0; *(ushort4*)(wit_hi+dst+4) = h1;
    *(ushort4*)(wit_lo+dst) = l0; *(ushort4*)(wit_lo+dst+4) = l1;
  }
}

// ---- one-time: transpose W_out (2048x512) -> WOT[n][k] hi/lo bf16 ----
__global__ __launch_bounds__(256) void k_woprep(const float* __restrict__ W_out,
    unsigned short* __restrict__ wot_hi, unsigned short* __restrict__ wot_lo){
  __shared__ float lds[64][68];
  int bk = blockIdx.x >> 3, bn = blockIdx.x & 7;
  int k0 = bk*64, n0 = bn*64;
  int tid = threadIdx.x;
  #pragma unroll
  for (int i=0;i<4;i++){
    int flat = tid + i*256;
    int k = flat >> 4, nq = flat & 15;
    float4 v = *(const float4*)(W_out + (size_t)(k0+k)*HH + n0 + nq*4);
    *(float4*)&lds[k][nq*4] = v;
  }
  __syncthreads();
  #pragma unroll
  for (int i=0;i<2;i++){
    int flat = tid + i*256;
    int n = flat >> 3, k8 = flat & 7;
    ushort4 h0, h1, l0, l1;
    unsigned short h[8], l[8];
    #pragma unroll
    for (int j=0;j<8;j++) split2(lds[k8*8+j][n], h[j], l[j]);
    h0.x=h[0];h0.y=h[1];h0.z=h[2];h0.w=h[3]; h1.x=h[4];h1.y=h[5];h1.z=h[6];h1.w=h[7];
    l0.x=l[0];l0.y=l[1];l0.z=l[2];l0.w=l[3]; l1.x=l[4];l1.y=l[5];l1.z=l[6];l1.w=l[7];
    size_t dst = (size_t)(n0+n)*H4 + k0 + k8*8;
    *(ushort4*)(wot_hi+dst) = h0; *(ushort4*)(wot_hi+dst+4) = h1;
    *(ushort4*)(wot_lo+dst) = l0; *(ushort4*)(wot_lo+dst+4) = l1;
  }
}

// ---- one-time: one context -> bf16 (launched twice) ----
__global__ __launch_bounds__(256) void k_ctx16(const float* __restrict__ src,
    unsigned short* __restrict__ dst){
  size_t off = ((size_t)blockIdx.x*256 + threadIdx.x)*8;
  float4 a = *(const float4*)(src + off);
  float4 c = *(const float4*)(src + off + 4);
  ushort4 u0, u1;
  u0.x=bf_rn(a.x); u0.y=bf_rn(a.y); u0.z=bf_rn(a.z); u0.w=bf_rn(a.w);
  u1.x=bf_rn(c.x); u1.y=bf_rn(c.y); u1.z=bf_rn(c.z); u1.w=bf_rn(c.w);
  *(ushort4*)(dst+off) = u0;
  *(ushort4*)(dst+off+4) = u1;
}

// ---- one-time: embeddings -> hi/lo planes for all t ----
__global__ __launch_bounds__(128) void k_prep(const int* __restrict__ inp,
    const float* __restrict__ emb0, const float* __restrict__ wemb,
    unsigned short* __restrict__ eh, unsigned short* __restrict__ el){
  int n = blockIdx.x; int t = n >> 6, b = n & 63;
  const float* src = (t==0) ? emb0 + (size_t)b*HH
                            : wemb + (size_t)inp[b*TT + (t-1)]*HH;
  float4 v = ((const float4*)src)[threadIdx.x];
  ushort4 h, l;
  split2(v.x,h.x,l.x); split2(v.y,h.y,l.y); split2(v.z,h.z,l.z); split2(v.w,h.w,l.w);
  size_t base = ((size_t)t*BB + b)*HH + threadIdx.x*4;
  *(ushort4*)(eh+base) = h; *(ushort4*)(el+base) = l;
}

// ---- one-time: state init (h planes -> hp/lp) ----
__global__ __launch_bounds__(256) void k_init(const float* __restrict__ th0,
    const float* __restrict__ tc0, const float* __restrict__ xh0,
    const float* __restrict__ xc0, const float* __restrict__ out0,
    float* __restrict__ ws, unsigned short* __restrict__ hp,
    unsigned short* __restrict__ lp){
  unsigned short* oh  = (unsigned short*)(ws + OFF_OH);
  unsigned short* ol  = (unsigned short*)(ws + OFF_OL);
  int which = blockIdx.x >> 5;
  int idx = (blockIdx.x & 31)*256 + threadIdx.x;
  if (which==0){ ((float4*)(ws+OFF_TC))[idx] = ((const float4*)tc0)[idx]; return; }
  if (which==1){ ((float4*)(ws+OFF_XC))[idx] = ((const float4*)xc0)[idx]; return; }
  const float* s = which==2? th0 : which==3? xh0 : out0;
  float4 v = ((const float4*)s)[idx];
  ushort4 h, l;
  split2(v.x,h.x,l.x); split2(v.y,h.y,l.y); split2(v.z,h.z,l.z); split2(v.w,h.w,l.w);
  if (which==4){
    *(ushort4*)(oh + (size_t)idx*4) = h; *(ushort4*)(ol + (size_t)idx*4) = l;
  } else {
    size_t base = (size_t)(which-2)*BB*HH + (size_t)idx*4;
    *(ushort4*)(hp+base) = h; *(ushort4*)(lp+base) = l;
  }
}

// ---- per step (fast): fused gate GEMM + LSTM. grid 256 = jt(32) x mt(8) ----
// Block: 16 batch-rows x 16 j-cols x 4 gates, full K; 4 waves split K=1536 4-way.
// WT layout UNCHANGED (proven). h planes double-buffered (read rs, write wsl).
__global__ __launch_bounds__(256) void k_gemmL(const unsigned short* __restrict__ wt_hi,
    const unsigned short* __restrict__ wt_lo, const unsigned short* __restrict__ eh,
    const unsigned short* __restrict__ el, const unsigned short* __restrict__ oh,
    const unsigned short* __restrict__ ol, unsigned short* __restrict__ hhp2,
    unsigned short* __restrict__ hlp2, float* __restrict__ ws,
    const float* __restrict__ bias, int t, int rs){
  __shared__ float accs[4][4][16][17];   // [wave][gate][row][col], 17 KB
  int tid = threadIdx.x, lane = tid & 63, wave = tid >> 6;
  int jt = blockIdx.x & 31, mt = blockIdx.x >> 5;
  int lm = lane & 15, lk = (lane >> 4) << 3;
  int wsl = rs ^ 1;
  f32x4 acc[4];
  #pragma unroll
  for (int g=0;g<4;g++) acc[g] = (f32x4){0.f,0.f,0.f,0.f};
  int r = mt*16 + lm;                       // global h-row (0..127): br*64+b
  size_t ebase = ((size_t)t*BB + (r & 63))*HH;
  size_t obase = (size_t)(r & 63)*HH;
  size_t hbase = ((size_t)rs*128 + r)*HH;
  size_t wb[4];
  #pragma unroll
  for (int g=0;g<4;g++) wb[g] = (size_t)(g*512 + jt*16 + lm)*1536;
  #pragma unroll
  for (int c=0;c<12;c++){
    int kg = wave*384 + c*32;               // this wave's K slice
    int sec = kg >> 9;
    int kk = (kg & 511) + lk;
    bf16x8 ah, al;
    if (sec==0){ ah = *(const bf16x8*)(eh + ebase + kk); al = *(const bf16x8*)(el + ebase + kk); }
    else if (sec==1){ ah = *(const bf16x8*)(oh + obase + kk); al = *(const bf16x8*)(ol + obase + kk); }
    else { ah = *(const bf16x8*)(hhp2 + hbase + kk); al = *(const bf16x8*)(hlp2 + hbase + kk); }
    int kw = kg + lk;
    #pragma unroll
    for (int g=0;g<4;g++){
      bf16x8 wh_ = *(const bf16x8*)(wt_hi + wb[g] + kw);
      bf16x8 wl_ = *(const bf16x8*)(wt_lo + wb[g] + kw);
      acc[g] = __builtin_amdgcn_mfma_f32_16x16x32_bf16(ah, wh_, acc[g], 0,0,0);
      acc[g] = __builtin_amdgcn_mfma_f32_16x16x32_bf16(ah, wl_, acc[g], 0,0,0);
      acc[g] = __builtin_amdgcn_mfma_f32_16x16x32_bf16(al, wh_, acc[g], 0,0,0);
    }
  }
  int lr4 = (lane >> 4) * 4;
  #pragma unroll
  for (int g=0;g<4;g++)
    #pragma unroll
    for (int q=0;q<4;q++)
      accs[wave][g][lr4+q][lm] = acc[g][q];
  __syncthreads();
  // epilogue: 256 threads = 16 rows x 16 j; 4-wave reduce + bias + LSTM
  int row = tid >> 4, jl = tid & 15;
  int jglob = jt*16 + jl;
  int rr = mt*16 + row;
  int br = rr >> 6, b = rr & 63;
  float g4[4];
  #pragma unroll
  for (int gi=0;gi<4;gi++)
    g4[gi] = accs[0][gi][row][jl] + accs[1][gi][row][jl]
           + accs[2][gi][row][jl] + accs[3][gi][row][jl] + bias[gi*512 + jglob];
  size_t coff = br ? OFF_XC : OFF_TC;
  float cold = ws[coff + (size_t)rs*BB*HH + (size_t)b*HH + jglob];
  float cn = sigm(g4[1])*cold + sigm(g4[0])*tanhf(g4[2]);
  float hn = sigm(g4[3])*tanhf(cn);
  ws[coff + (size_t)wsl*BB*HH + (size_t)b*HH + jglob] = cn;
  unsigned short h_, l_;
  split2(hn, h_, l_);
  size_t hidx = ((size_t)wsl*128 + rr)*HH + jglob;
  hhp2[hidx] = h_; hlp2[hidx] = l_;
}

// ---- per step: tgt = h @ W_in, full K, FINAL. grid 64 = cn(8) x mt(8) ----
__global__ __launch_bounds__(256) void k_tgtB(const unsigned short* __restrict__ wit_hi,
    const unsigned short* __restrict__ wit_lo, const unsigned short* __restrict__ hhp,
    const unsigned short* __restrict__ hlp, float* __restrict__ tgt){
  int tid = threadIdx.x, lane = tid & 63, wave = tid >> 6;
  int cn = blockIdx.x & 7, mt = blockIdx.x >> 3;
  int lm = lane & 15, lk = (lane >> 4) << 3;
  f32x4 acc = (f32x4){0.f,0.f,0.f,0.f};
  size_t abase = (size_t)(mt*16 + lm)*HH;
  size_t wb = (size_t)(cn*64 + wave*16 + lm)*HH;
  #pragma unroll
  for (int c=0;c<16;c++){
    int kc = c*32 + lk;
    bf16x8 ah  = *(const bf16x8*)(hhp + abase + kc);
    bf16x8 al  = *(const bf16x8*)(hlp + abase + kc);
    bf16x8 wh_ = *(const bf16x8*)(wit_hi + wb + kc);
    bf16x8 wl_ = *(const bf16x8*)(wit_lo + wb + kc);
    acc = __builtin_amdgcn_mfma_f32_16x16x32_bf16(ah, wh_, acc, 0,0,0);
    acc = __builtin_amdgcn_mfma_f32_16x16x32_bf16(ah, wl_, acc, 0,0,0);
    acc = __builtin_amdgcn_mfma_f32_16x16x32_bf16(al, wh_, acc, 0,0,0);
  }
  int lr4 = (lane >> 4) * 4;
  int col = cn*64 + wave*16 + lm;
  #pragma unroll
  for (int q=0;q<4;q++)
    tgt[(size_t)(mt*16 + lr4 + q)*HH + col] = acc[q];
}

// ---- per step: FLASH-FUSED attention partial (single ctx read, online softmax) ----
__global__ __launch_bounds__(512, 8) void k_attn(const float* __restrict__ tree_ctx,
    const float* __restrict__ text_ctx, const unsigned short* __restrict__ ctx16,
    float* __restrict__ ws, int use16){
  int blk = blockIdx.x;
  int sh = blk & 7, b = (blk>>3) & 63, branch = blk >> 9;
  int tid = threadIdx.x, lane = tid & 63, wave = tid >> 6;
  __shared__ float tgt_s[512];
  __shared__ float accs[8][512];
  __shared__ float wm_s[8], wl_s[8];
  int row128 = branch*64 + b;
  if (tid < 128)
    ((float4*)tgt_s)[tid] = ((const float4*)(ws + OFF_TGTP + (size_t)row128*HH))[tid];
  __syncthreads();
  const size_t CH = (size_t)BB*SS*HH;
  const float* ctxf = (branch? text_ctx : tree_ctx) + ((size_t)b*SS + sh*50)*HH;
  const unsigned short* c16 = ctx16 + (branch? CH:0) + ((size_t)b*SS + sh*50)*HH;
  float4 ta = *(const float4*)&tgt_s[lane*8];
  float4 tb = *(const float4*)&tgt_s[lane*8+4];
  float m = -INFINITY, l = 0.f;
  float a[8] = {0,0,0,0,0,0,0,0};
  if (use16){
    for (int r = wave; r < 50; r += 8){
      uint4 u = *(const uint4*)(c16 + (size_t)r*HH + lane*8);
      float v0=blo(u.x), v1=bhi(u.x), v2=blo(u.y), v3=bhi(u.y);
      float v4=blo(u.z), v5=bhi(u.z), v6=blo(u.w), v7=bhi(u.w);
      float p = v0*ta.x + v1*ta.y + v2*ta.z + v3*ta.w
              + v4*tb.x + v5*tb.y + v6*tb.z + v7*tb.w;
      #pragma unroll
      for (int off=32; off; off>>=1) p += __shfl_xor(p, off, 64);
      float mn = fmaxf(m, p);
      float scale = __expf(m - mn);
      float e = __expf(p - mn);
      l = l*scale + e;
      a[0] = a[0]*scale + e*v0; a[1] = a[1]*scale + e*v1;
      a[2] = a[2]*scale + e*v2; a[3] = a[3]*scale + e*v3;
      a[4] = a[4]*scale + e*v4; a[5] = a[5]*scale + e*v5;
      a[6] = a[6]*scale + e*v6; a[7] = a[7]*scale + e*v7;
      m = mn;
    }
  } else {
    for (int r = wave; r < 50; r += 8){
      const float* crow = ctxf + (size_t)r*HH + lane*8;
      float4 ca = *(const float4*)crow;
      float4 cb = *(const float4*)(crow+4);
      float p = ca.x*ta.x + ca.y*ta.y + ca.z*ta.z + ca.w*ta.w
              + cb.x*tb.x + cb.y*tb.y + cb.z*tb.z + cb.w*tb.w;
      #pragma unroll
      for (int off=32; off; off>>=1) p += __shfl_xor(p, off, 64);
      float mn = fmaxf(m, p);
      float scale = __expf(m - mn);
      float e = __expf(p - mn);
      l = l*scale + e;
      a[0] = a[0]*scale + e*ca.x; a[1] = a[1]*scale + e*ca.y;
      a[2] = a[2]*scale + e*ca.z; a[3] = a[3]*scale + e*ca.w;
      a[4] = a[4]*scale + e*cb.x; a[5] = a[5]*scale + e*cb.y;
      a[6] = a[6]*scale + e*cb.z; a[7] = a[7]*scale + e*cb.w;
      m = mn;
    }
  }
  if (lane==0){ wm_s[wave] = m; wl_s[wave] = l; }
  #pragma unroll
  for (int j=0;j<8;j++) accs[wave][lane*8+j] = a[j];
  __syncthreads();
  float M = wm_s[0];
  #pragma unroll
  for (int w8=1;w8<8;w8++) M = fmaxf(M, wm_s[w8]);
  float s = 0.f;
  #pragma unroll
  for (int w8=0;w8<8;w8++) s += accs[w8][tid] * __expf(wm_s[w8] - M);
  int pidx = (branch*64 + b)*8 + sh;
  ws[OFF_PACC + (size_t)pidx*HH + tid] = s;
  if (tid==0){
    float L = 0.f;
    #pragma unroll
    for (int w8=0;w8<8;w8++) L += wl_s[w8]*__expf(wm_s[w8] - M);
    ws[OFF_PML + (size_t)pidx*2]   = M;
    ws[OFF_PML + (size_t)pidx*2+1] = L;
  }
}

// ---- per step: merge attn partials -> comb hi/lo bf16 [64][1024]. grid 64 ----
__global__ __launch_bounds__(256) void k_outA(float* __restrict__ ws){
  __shared__ float ce_s[2][8];
  int b = blockIdx.x, tid = threadIdx.x;
  if (tid < 2){
    int p0 = (tid*64 + b)*8;
    float mv[8], lv[8];
    float M = -INFINITY;
    #pragma unroll
    for (int i=0;i<8;i++){
      mv[i] = ws[OFF_PML + (size_t)(p0+i)*2];
      lv[i] = ws[OFF_PML + (size_t)(p0+i)*2+1];
      M = fmaxf(M, mv[i]);
    }
    float L = 0.f, ev[8];
    #pragma unroll
    for (int i=0;i<8;i++){ ev[i] = __expf(mv[i]-M); L += lv[i]*ev[i]; }
    #pragma unroll
    for (int i=0;i<8;i++) ce_s[tid][i] = ev[i]/L;
  }
  __syncthreads();
  int h = tid*4;
  int sec = h >> 9, hs = h & 511;
  int p0 = (sec*64 + b)*8;
  float4 v = {0,0,0,0};
  #pragma unroll
  for (int p=0;p<8;p++){
    float4 a = *(const float4*)(ws + OFF_PACC + (size_t)(p0+p)*HH + hs);
    float cw = ce_s[sec][p];
    v.x += a.x*cw; v.y += a.y*cw; v.z += a.z*cw; v.w += a.w*cw;
  }
  ushort4 hv, lv;
  split2(v.x,hv.x,lv.x); split2(v.y,hv.y,lv.y); split2(v.z,hv.z,lv.z); split2(v.w,hv.w,lv.w);
  unsigned short* ch = (unsigned short*)(ws + OFF_COMBH);
  unsigned short* cl = (unsigned short*)(ws + OFF_COMBL);
  *(ushort4*)(ch + (size_t)b*1024 + h) = hv;
  *(ushort4*)(cl + (size_t)b*1024 + h) = lv;
}

// ---- per step (fast): fused out GEMM + tanh + store + O planes.
// grid 128 = nt(32) x mt(4); 4 waves split K=2048 4-way, LDS reduce, epilogue.
__global__ __launch_bounds__(256) void k_outBF(const unsigned short* __restrict__ wot_hi,
    const unsigned short* __restrict__ wot_lo, const unsigned short* __restrict__ combh,
    const unsigned short* __restrict__ combl, const unsigned short* __restrict__ hhp,
    const unsigned short* __restrict__ hlp, float* __restrict__ dout,
    unsigned short* __restrict__ oh, unsigned short* __restrict__ ol, int t){
  __shared__ float accs[4][16][17];
  int tid = threadIdx.x, lane = tid & 63, wave = tid >> 6;
  int nt = blockIdx.x & 31, mt = blockIdx.x >> 5;
  int lm = lane & 15, lk = (lane >> 4) << 3;
  f32x4 acc = (f32x4){0.f,0.f,0.f,0.f};
  int b = mt*16 + lm;
  int col = nt*16 + lm;
  size_t wb = (size_t)col*H4 + (size_t)wave*512;
  const unsigned short *pa_h, *pa_l;
  size_t abase;
  if (wave < 2){ pa_h = combh; pa_l = combl; abase = (size_t)b*1024 + (size_t)wave*512; }
  else         { pa_h = hhp;   pa_l = hlp;   abase = ((size_t)(wave-2)*64 + b)*HH; }
  #pragma unroll
  for (int c=0;c<16;c++){
    int kk = c*32 + lk;
    bf16x8 ah  = *(const bf16x8*)(pa_h + abase + kk);
    bf16x8 al  = *(const bf16x8*)(pa_l + abase + kk);
    bf16x8 wh_ = *(const bf16x8*)(wot_hi + wb + kk);
    bf16x8 wl_ = *(const bf16x8*)(wot_lo + wb + kk);
    acc = __builtin_amdgcn_mfma_f32_16x16x32_bf16(ah, wh_, acc, 0,0,0);
    acc = __builtin_amdgcn_mfma_f32_16x16x32_bf16(ah, wl_, acc, 0,0,0);
    acc = __builtin_amdgcn_mfma_f32_16x16x32_bf16(al, wh_, acc, 0,0,0);
  }
  int lr4 = (lane >> 4) * 4;
  #pragma unroll
  for (int q=0;q<4;q++) accs[wave][lr4+q][lm] = acc[q];
  __syncthreads();
  int row = tid >> 4, colL = tid & 15;
  float s = accs[0][row][colL] + accs[1][row][colL]
          + accs[2][row][colL] + accs[3][row][colL];
  float v = tanhf(s);
  int bb = mt*16 + row, cc = nt*16 + colL;
  dout[((size_t)bb*TT + t)*HH + cc] = v;
  unsigned short h_, l_;
  split2(v, h_, l_);
  oh[(size_t)bb*HH + cc] = h_;
  ol[(size_t)bb*HH + cc] = l_;
}

// ======== fallback-path kernels (small ws): proven round-12 versions ========
__global__ __launch_bounds__(256) void k_gemm(const unsigned short* __restrict__ wt_hi,
    const unsigned short* __restrict__ wt_lo, const unsigned short* __restrict__ eh,
    const unsigned short* __restrict__ el, const unsigned short* __restrict__ oh,
    const unsigned short* __restrict__ ol, const unsigned short* __restrict__ hhp,
    const unsigned short* __restrict__ hlp, float* __restrict__ gpart, int t){
  int tid = threadIdx.x, lane = tid & 63, wave = tid >> 6;
  int bn = blockIdx.x & 31, ks = blockIdx.x >> 5;
  int lm = lane & 15, lk = (lane >> 4) << 3;
  f32x4 acc[2][4];
  #pragma unroll
  for (int i=0;i<2;i++)
    #pragma unroll
    for (int j=0;j<4;j++) acc[i][j] = (f32x4){0.f,0.f,0.f,0.f};
  size_t ebase[2], obase[2], hbase[2];
  #pragma unroll
  for (int i=0;i<2;i++){
    int r = (wave*2 + i)*16 + lm;
    int b = r & 63, br = r >> 6;
    ebase[i] = ((size_t)t*BB + b)*HH;
    obase[i] = (size_t)b*HH;
    hbase[i] = ((size_t)br*BB + b)*HH;
  }
  size_t wb[4];
  #pragma unroll
  for (int j=0;j<4;j++) wb[j] = (size_t)(bn*64 + j*16 + lm)*1536;
  #pragma unroll
  for (int c=0;c<6;c++){
    int kc = ks*192 + c*32;
    int sec = kc >> 9;
    int kk = (kc & 511) + lk;
    const unsigned short* ph = sec==0? eh : sec==1? oh : hhp;
    const unsigned short* pl = sec==0? el : sec==1? ol : hlp;
    bf16x8 ah[2], al[2], wh_[4], wl_[4];
    #pragma unroll
    for (int i=0;i<2;i++){
      size_t off = (sec==0? ebase[i] : sec==1? obase[i] : hbase[i]) + kk;
      ah[i] = *(const bf16x8*)(ph + off);
      al[i] = *(const bf16x8*)(pl + off);
    }
    int kw = kc + lk;
    #pragma unroll
    for (int j=0;j<4;j++){
      wh_[j] = *(const bf16x8*)(wt_hi + wb[j] + kw);
      wl_[j] = *(const bf16x8*)(wt_lo + wb[j] + kw);
    }
    #pragma unroll
    for (int i=0;i<2;i++)
      #pragma unroll
      for (int j=0;j<4;j++){
        acc[i][j] = __builtin_amdgcn_mfma_f32_16x16x32_bf16(ah[i], wh_[j], acc[i][j], 0,0,0);
        acc[i][j] = __builtin_amdgcn_mfma_f32_16x16x32_bf16(ah[i], wl_[j], acc[i][j], 0,0,0);
        acc[i][j] = __builtin_amdgcn_mfma_f32_16x16x32_bf16(al[i], wh_[j], acc[i][j], 0,0,0);
      }
  }
  int lr4 = (lane >> 4) * 4;
  #pragma unroll
  for (int i=0;i<2;i++){
    int m0 = (wave*2+i)*16;
    #pragma unroll
    for (int j=0;j<4;j++){
      int col = bn*64 + j*16 + lm;
      #pragma unroll
      for (int q=0;q<4;q++){
        int row = m0 + lr4 + q;
        gpart[((size_t)ks*128 + row)*H4 + col] = acc[i][j][q];
      }
    }
  }
}

__global__ __launch_bounds__(256) void k_lstm(float* __restrict__ ws,
    const float* __restrict__ bias, int rs){
  int gid = blockIdx.x*256 + threadIdx.x;
  int b = gid >> 9, j = gid & 511;
  int wsl = rs ^ 1;
  const float* gp = ws + OFF_G;
  unsigned short* hhp = (unsigned short*)(ws + OFF_HHP);
  unsigned short* hlp = (unsigned short*)(ws + OFF_HLP);
  #pragma unroll
  for (int br=0;br<2;br++){
    float g0=0.f,g1=0.f,g2=0.f,g3=0.f;
    #pragma unroll
    for (int ks=0;ks<8;ks++){
      size_t base = ((size_t)ks*128 + br*64 + b)*H4 + j;
      g0 += gp[base]; g1 += gp[base+512]; g2 += gp[base+1024]; g3 += gp[base+1536];
    }
    g0 += bias[j]; g1 += bias[512+j]; g2 += bias[1024+j]; g3 += bias[1536+j];
    size_t hoff = (br? OFF_XH : OFF_TH), coff = (br? OFF_XC : OFF_TC);
    float cold = ws[coff + (size_t)rs*BB*HH + (size_t)b*HH + j];
    float cn = sigm(g1)*cold + sigm(g0)*tanhf(g2);
    float hn = sigm(g3)*tanhf(cn);
    ws[coff + (size_t)wsl*BB*HH + (size_t)b*HH + j] = cn;
    ws[hoff + (size_t)wsl*BB*HH + (size_t)b*HH + j] = hn;
    unsigned short h_, l_;
    split2(hn, h_, l_);
    hhp[(size_t)(br*64+b)*HH + j] = h_;
    hlp[(size_t)(br*64+b)*HH + j] = l_;
  }
}

__global__ __launch_bounds__(256) void k_outB(const float* __restrict__ W_out,
    float* __restrict__ ws, int wsl){
  __shared__ float comb_s[16][256];
  __shared__ float ce_s[16][8];
  int tid = threadIdx.x, lane = tid & 63, wave = tid >> 6;
  int blk = blockIdx.x;
  int ct = blk & 7, bg = (blk>>3)&3, ks = blk>>5;
  int b0 = bg*16;
  int k0 = ks*256;
  int sec = ks >> 1;
  int kk0 = (ks & 1)*256;
  int c = ct*64 + lane;
  if (sec < 2){
    if (tid < 16){
      int b = b0 + tid;
      int p0 = (sec*64 + b)*8;
      float mv[8], lv[8];
      float M = -INFINITY;
      #pragma unroll
      for (int i=0;i<8;i++){
        mv[i] = ws[OFF_PML + (size_t)(p0+i)*2];
        lv[i] = ws[OFF_PML + (size_t)(p0+i)*2+1];
        M = fmaxf(M, mv[i]);
      }
      float L = 0.f, ev[8];
      #pragma unroll
      for (int i=0;i<8;i++){ ev[i] = __expf(mv[i]-M); L += lv[i]*ev[i]; }
      #pragma unroll
      for (int i=0;i<8;i++) ce_s[tid][i] = ev[i]/L;
    }
    __syncthreads();
  }
  #pragma unroll
  for (int i=0;i<4;i++){
    int flat = tid + i*256;
    int row = flat >> 6;
    int q   = flat & 63;
    int b = b0 + row;
    int h = kk0 + q*4;
    float4 v;
    if (sec < 2){
      int p0 = (sec*64 + b)*8;
      v.x = 0.f; v.y = 0.f; v.z = 0.f; v.w = 0.f;
      #pragma unroll
      for (int p=0;p<8;p++){
        float4 a = *(const float4*)(ws + OFF_PACC + (size_t)(p0+p)*HH + h);
        float cw = ce_s[row][p];
        v.x += a.x*cw; v.y += a.y*cw; v.z += a.z*cw; v.w += a.w*cw;
      }
    } else {
      size_t hoff = (sec==2 ? OFF_TH : OFF_XH) + (size_t)wsl*BB*HH;
      v = *(const float4*)(ws + hoff + (size_t)b*HH + h);
    }
    *(float4*)&comb_s[row][q*4] = v;
  }
  __syncthreads();
  float acc[4] = {0,0,0,0};
  #pragma unroll 4
  for (int k=0;k<256;k++){
    float wv = W_out[(size_t)(k0+k)*HH + c];
    #pragma unroll
    for (int i=0;i<4;i++) acc[i] += comb_s[wave*4+i][k]*wv;
  }
  #pragma unroll
  for (int i=0;i<4;i++){
    int b = b0 + wave*4 + i;
    ws[OFF_PART + ((size_t)ks*BB + b)*HH + c] = acc[i];
  }
}

__global__ __launch_bounds__(256) void k_outC(float* __restrict__ ws,
    float* __restrict__ dout, int t){
  int gid = blockIdx.x*256 + threadIdx.x;
  int b = gid >> 7, cq = gid & 127;
  int c0 = cq*4;
  float4 s = {0,0,0,0};
  #pragma unroll
  for (int ks=0;ks<8;ks++){
    float4 p = *(const float4*)(ws + OFF_PART + ((size_t)ks*BB + b)*HH + c0);
    s.x += p.x; s.y += p.y; s.z += p.z; s.w += p.w;
  }
  float4 o;
  o.x = tanhf(s.x); o.y = tanhf(s.y); o.z = tanhf(s.z); o.w = tanhf(s.w);
  *(float4*)(dout + ((size_t)b*TT + t)*HH + c0) = o;
  ushort4 h, l;
  split2(o.x,h.x,l.x); split2(o.y,h.y,l.y); split2(o.z,h.z,l.z); split2(o.w,h.w,l.w);
  unsigned short* oh = (unsigned short*)(ws + OFF_OH);
  unsigned short* ol = (unsigned short*)(ws + OFF_OL);
  *(ushort4*)(oh + (size_t)b*HH + c0) = h;
  *(ushort4*)(ol + (size_t)b*HH + c0) = l;
}

extern "C" void kernel_launch(void* const* d_in, const int* in_sizes, int n_in,
                              void* d_out, int out_size, void* d_ws, size_t ws_size,
                              hipStream_t stream){
  const int*   inp   = (const int*)  d_in[0];
  const float* emb0  = (const float*)d_in[1];
  const float* out0  = (const float*)d_in[2];
  const float* th0   = (const float*)d_in[3];
  const float* tc0   = (const float*)d_in[4];
  const float* trctx = (const float*)d_in[5];
  const float* xh0   = (const float*)d_in[6];
  const float* xc0   = (const float*)d_in[7];
  const float* txctx = (const float*)d_in[8];
  const float* wemb  = (const float*)d_in[9];
  const float* Wx    = (const float*)d_in[10];
  const float* Wh    = (const float*)d_in[11];
  const float* bias  = (const float*)d_in[12];
  const float* W_in  = (const float*)d_in[13];
  const float* W_out = (const float*)d_in[14];
  float* ws  = (float*)d_ws;
  float* out = (float*)d_out;
  unsigned short* wt_hi  = (unsigned short*)(ws + OFF_WT_HI);
  unsigned short* wt_lo  = (unsigned short*)(ws + OFF_WT_LO);
  unsigned short* wit_hi = (unsigned short*)(ws + OFF_WIT_HI);
  unsigned short* wit_lo = (unsigned short*)(ws + OFF_WIT_LO);
  unsigned short* wot_hi = (unsigned short*)(ws + OFF_WOT_HI);
  unsigned short* wot_lo = (unsigned short*)(ws + OFF_WOT_LO);
  unsigned short* combh  = (unsigned short*)(ws + OFF_COMBH);
  unsigned short* combl  = (unsigned short*)(ws + OFF_COMBL);
  unsigned short* eh  = (unsigned short*)(ws + OFF_EH);
  unsigned short* el  = (unsigned short*)(ws + OFF_EL);
  unsigned short* oh  = (unsigned short*)(ws + OFF_OH);
  unsigned short* ol  = (unsigned short*)(ws + OFF_OL);
  unsigned short* hhp = (unsigned short*)(ws + OFF_HHP);
  unsigned short* hlp = (unsigned short*)(ws + OFF_HLP);
  unsigned short* hhp2 = (unsigned short*)(ws + OFF_HHP2);
  unsigned short* hlp2 = (unsigned short*)(ws + OFF_HLP2);
  unsigned short* ctx16 = (unsigned short*)(ws + OFF_CTX16);
  float* gpart = ws + OFF_G;
  float* tgt   = ws + OFF_TGTP;
  int use16 = (ws_size >= (size_t)WS_NEED_F  * 4u) ? 1 : 0;
  int fast  = (ws_size >= (size_t)WS_NEED2_F * 4u) ? 1 : 0;
  const size_t CH = (size_t)BB*SS*HH;

  hipLaunchKernelGGL(k_wprep,  dim3(768),   dim3(256), 0, stream, Wx, Wh, wt_hi, wt_lo);
  hipLaunchKernelGGL(k_wiprep, dim3(64),    dim3(256), 0, stream, W_in, wit_hi, wit_lo);
  if (fast)
    hipLaunchKernelGGL(k_woprep, dim3(256), dim3(256), 0, stream, W_out, wot_hi, wot_lo);
  if (use16){
    hipLaunchKernelGGL(k_ctx16, dim3(6400), dim3(256), 0, stream, trctx, ctx16);
    hipLaunchKernelGGL(k_ctx16, dim3(6400), dim3(256), 0, stream, txctx, ctx16 + CH);
  }
  hipLaunchKernelGGL(k_prep,   dim3(TT*BB), dim3(128), 0, stream, inp, emb0, wemb, eh, el);
  hipLaunchKernelGGL(k_init,   dim3(160),   dim3(256), 0, stream, th0, tc0, xh0, xc0, out0,
                     ws, fast? hhp2 : hhp, fast? hlp2 : hlp);
  for (int t=0; t<TT; t++){
    int rs = t & 1, wsl = rs ^ 1;
    if (fast){
      unsigned short* hh_w = hhp2 + (size_t)wsl*128*HH;
      unsigned short* hl_w = hlp2 + (size_t)wsl*128*HH;
      hipLaunchKernelGGL(k_gemmL, dim3(256), dim3(256), 0, stream,
                         wt_hi, wt_lo, eh, el, oh, ol, hhp2, hlp2, ws, bias, t, rs);
      hipLaunchKernelGGL(k_tgtB, dim3(64), dim3(256), 0, stream, wit_hi, wit_lo, hh_w, hl_w, tgt);
      hipLaunchKernelGGL(k_attn, dim3(1024), dim3(512), 0, stream, trctx, txctx, ctx16, ws, use16);
      hipLaunchKernelGGL(k_outA, dim3(64), dim3(256), 0, stream, ws);
      hipLaunchKernelGGL(k_outBF, dim3(128), dim3(256), 0, stream,
                         wot_hi, wot_lo, combh, combl, hh_w, hl_w, out, oh, ol, t);
    } else {
      hipLaunchKernelGGL(k_gemm, dim3(256), dim3(256), 0, stream,
                         wt_hi, wt_lo, eh, el, oh, ol, hhp, hlp, gpart, t);
      hipLaunchKernelGGL(k_lstm, dim3(128), dim3(256), 0, stream, ws, bias, rs);
      hipLaunchKernelGGL(k_tgtB, dim3(64),  dim3(256), 0, stream, wit_hi, wit_lo, hhp, hlp, tgt);
      hipLaunchKernelGGL(k_attn, dim3(1024), dim3(512), 0, stream, trctx, txctx, ctx16, ws, use16);
      hipLaunchKernelGGL(k_outB, dim3(256), dim3(256), 0, stream, W_out, ws, wsl);
      hipLaunchKernelGGL(k_outC, dim3(32),  dim3(256), 0, stream, ws, out, t);
    }
  }
}

// Round 14
// 1528.237 us; speedup vs baseline: 1.0768x; 1.0768x over previous
//
#include <hip/hip_runtime.h>
#include <hip/hip_bf16.h>
#include <math.h>

#define BB 64
#define TT 32
#define HH 512
#define H2 1024
#define H4 2048
#define SS 400

// ---- workspace layout (float offsets) ----
#define OFF_WT_HI 0u          // WT hi: [2048 n][1536 k] bf16 = 1572864 floats
#define OFF_WT_LO 1572864u
#define OFF_WIT_HI 3145728u   // W_inT hi: [512 n][512 k] bf16 = 131072 floats
#define OFF_WIT_LO 3276800u
#define OFF_EH    3407872u    // E hi: [32][64][512] bf16
#define OFF_EL    3932160u
#define OFF_OH    4456448u    // O planes [64][512] bf16
#define OFF_OL    4472832u
#define OFF_HHP   4489216u    // h planes [2br*64][512] bf16
#define OFF_HLP   4521984u
#define OFF_TC    4554752u    // fp32 [2 slot][64][512]
#define OFF_XC    4620288u
#define OFF_TH    4685824u
#define OFF_XH    4751360u
#define OFF_G     4816896u    // gpart [8ks][128][2048] fp32 = 2097152
#define OFF_TGTP  6914048u    // tgt FINAL [128][512] fp32
#define OFF_PACC  7438336u    // [1024 pidx][512]
#define OFF_PML   7962624u    // [1024][2]
#define OFF_CTX16 7964672u    // bf16 ctx [2][64][400][512]
#define WS_NEED_F 21071872u
#define OFF_WOT_HI 21071872u  // W_outT hi: [512 n][2048 k] bf16
#define OFF_WOT_LO 21596160u
#define OFF_COMBH  22120448u  // comb hi: [64][1024] bf16
#define OFF_COMBL  22153216u
#define WS_NEED2_F 22185984u
#define OFF_PART  OFF_G       // fallback k_outB partials alias consumed G

typedef short bf16x8 __attribute__((ext_vector_type(8)));
typedef float f32x4  __attribute__((ext_vector_type(4)));

__device__ __forceinline__ float sigm(float x){ return 1.f/(1.f+__expf(-x)); }

__device__ __forceinline__ unsigned short bf_rn(float x){
  unsigned int u = __float_as_uint(x);
  return (unsigned short)((u + 0x7fffu + ((u>>16)&1u)) >> 16);
}
__device__ __forceinline__ void split2(float x, unsigned short &h, unsigned short &l){
  h = bf_rn(x);
  float hf = __uint_as_float(((unsigned int)h)<<16);
  l = bf_rn(x - hf);
}
__device__ __forceinline__ float blo(unsigned int u){ return __uint_as_float(u<<16); }
__device__ __forceinline__ float bhi(unsigned int u){ return __uint_as_float(u & 0xffff0000u); }

// ---- one-time: transpose W=[Wx;Wh] (1536x2048) -> WT[n][k] hi/lo bf16 ----
__global__ __launch_bounds__(256) void k_wprep(const float* __restrict__ Wx,
    const float* __restrict__ Wh, unsigned short* __restrict__ wt_hi,
    unsigned short* __restrict__ wt_lo){
  __shared__ float lds[64][68];
  int bk = blockIdx.x >> 5, bn = blockIdx.x & 31;
  int k0 = bk*64, n0 = bn*64;
  int tid = threadIdx.x;
  #pragma unroll
  for (int i=0;i<4;i++){
    int flat = tid + i*256;
    int k = flat >> 4, nq = flat & 15;
    int kg = k0 + k;
    const float* srow = (kg < 1024) ? Wx + (size_t)kg*H4 : Wh + (size_t)(kg-1024)*H4;
    float4 v = *(const float4*)(srow + n0 + nq*4);
    *(float4*)&lds[k][nq*4] = v;
  }
  __syncthreads();
  #pragma unroll
  for (int i=0;i<2;i++){
    int flat = tid + i*256;
    int n = flat >> 3, k8 = flat & 7;
    ushort4 h0, h1, l0, l1;
    unsigned short h[8], l[8];
    #pragma unroll
    for (int j=0;j<8;j++) split2(lds[k8*8+j][n], h[j], l[j]);
    h0.x=h[0];h0.y=h[1];h0.z=h[2];h0.w=h[3]; h1.x=h[4];h1.y=h[5];h1.z=h[6];h1.w=h[7];
    l0.x=l[0];l0.y=l[1];l0.z=l[2];l0.w=l[3]; l1.x=l[4];l1.y=l[5];l1.z=l[6];l1.w=l[7];
    size_t dst = (size_t)(n0+n)*1536 + k0 + k8*8;
    *(ushort4*)(wt_hi+dst) = h0; *(ushort4*)(wt_hi+dst+4) = h1;
    *(ushort4*)(wt_lo+dst) = l0; *(ushort4*)(wt_lo+dst+4) = l1;
  }
}

// ---- one-time: transpose W_in (512x512) -> WIT[n][k] hi/lo bf16 ----
__global__ __launch_bounds__(256) void k_wiprep(const float* __restrict__ W_in,
    unsigned short* __restrict__ wit_hi, unsigned short* __restrict__ wit_lo){
  __shared__ float lds[64][68];
  int bk = blockIdx.x >> 3, bn = blockIdx.x & 7;
  int k0 = bk*64, n0 = bn*64;
  int tid = threadIdx.x;
  #pragma unroll
  for (int i=0;i<4;i++){
    int flat = tid + i*256;
    int k = flat >> 4, nq = flat & 15;
    float4 v = *(const float4*)(W_in + (size_t)(k0+k)*HH + n0 + nq*4);
    *(float4*)&lds[k][nq*4] = v;
  }
  __syncthreads();
  #pragma unroll
  for (int i=0;i<2;i++){
    int flat = tid + i*256;
    int n = flat >> 3, k8 = flat & 7;
    ushort4 h0, h1, l0, l1;
    unsigned short h[8], l[8];
    #pragma unroll
    for (int j=0;j<8;j++) split2(lds[k8*8+j][n], h[j], l[j]);
    h0.x=h[0];h0.y=h[1];h0.z=h[2];h0.w=h[3]; h1.x=h[4];h1.y=h[5];h1.z=h[6];h1.w=h[7];
    l0.x=l[0];l0.y=l[1];l0.z=l[2];l0.w=l[3]; l1.x=l[4];l1.y=l[5];l1.z=l[6];l1.w=l[7];
    size_t dst = (size_t)(n0+n)*HH + k0 + k8*8;
    *(ushort4*)(wit_hi+dst) = h0; *(ushort4*)(wit_hi+dst+4) = h1;
    *(ushort4*)(wit_lo+dst) = l0; *(ushort4*)(wit_lo+dst+4) = l1;
  }
}

// ---- one-time: transpose W_out (2048x512) -> WOT[n][k] hi/lo bf16 ----
__global__ __launch_bounds__(256) void k_woprep(const float* __restrict__ W_out,
    unsigned short* __restrict__ wot_hi, unsigned short* __restrict__ wot_lo){
  __shared__ float lds[64][68];
  int bk = blockIdx.x >> 3, bn = blockIdx.x & 7;
  int k0 = bk*64, n0 = bn*64;
  int tid = threadIdx.x;
  #pragma unroll
  for (int i=0;i<4;i++){
    int flat = tid + i*256;
    int k = flat >> 4, nq = flat & 15;
    float4 v = *(const float4*)(W_out + (size_t)(k0+k)*HH + n0 + nq*4);
    *(float4*)&lds[k][nq*4] = v;
  }
  __syncthreads();
  #pragma unroll
  for (int i=0;i<2;i++){
    int flat = tid + i*256;
    int n = flat >> 3, k8 = flat & 7;
    ushort4 h0, h1, l0, l1;
    unsigned short h[8], l[8];
    #pragma unroll
    for (int j=0;j<8;j++) split2(lds[k8*8+j][n], h[j], l[j]);
    h0.x=h[0];h0.y=h[1];h0.z=h[2];h0.w=h[3]; h1.x=h[4];h1.y=h[5];h1.z=h[6];h1.w=h[7];
    l0.x=l[0];l0.y=l[1];l0.z=l[2];l0.w=l[3]; l1.x=l[4];l1.y=l[5];l1.z=l[6];l1.w=l[7];
    size_t dst = (size_t)(n0+n)*H4 + k0 + k8*8;
    *(ushort4*)(wot_hi+dst) = h0; *(ushort4*)(wot_hi+dst+4) = h1;
    *(ushort4*)(wot_lo+dst) = l0; *(ushort4*)(wot_lo+dst+4) = l1;
  }
}

// ---- one-time: one context -> bf16 (launched twice) ----
__global__ __launch_bounds__(256) void k_ctx16(const float* __restrict__ src,
    unsigned short* __restrict__ dst){
  size_t off = ((size_t)blockIdx.x*256 + threadIdx.x)*8;
  float4 a = *(const float4*)(src + off);
  float4 c = *(const float4*)(src + off + 4);
  ushort4 u0, u1;
  u0.x=bf_rn(a.x); u0.y=bf_rn(a.y); u0.z=bf_rn(a.z); u0.w=bf_rn(a.w);
  u1.x=bf_rn(c.x); u1.y=bf_rn(c.y); u1.z=bf_rn(c.z); u1.w=bf_rn(c.w);
  *(ushort4*)(dst+off) = u0;
  *(ushort4*)(dst+off+4) = u1;
}

// ---- one-time: embeddings -> hi/lo planes for all t ----
__global__ __launch_bounds__(128) void k_prep(const int* __restrict__ inp,
    const float* __restrict__ emb0, const float* __restrict__ wemb,
    unsigned short* __restrict__ eh, unsigned short* __restrict__ el){
  int n = blockIdx.x; int t = n >> 6, b = n & 63;
  const float* src = (t==0) ? emb0 + (size_t)b*HH
                            : wemb + (size_t)inp[b*TT + (t-1)]*HH;
  float4 v = ((const float4*)src)[threadIdx.x];
  ushort4 h, l;
  split2(v.x,h.x,l.x); split2(v.y,h.y,l.y); split2(v.z,h.z,l.z); split2(v.w,h.w,l.w);
  size_t base = ((size_t)t*BB + b)*HH + threadIdx.x*4;
  *(ushort4*)(eh+base) = h; *(ushort4*)(el+base) = l;
}

// ---- one-time: state init ----
__global__ __launch_bounds__(256) void k_init(const float* __restrict__ th0,
    const float* __restrict__ tc0, const float* __restrict__ xh0,
    const float* __restrict__ xc0, const float* __restrict__ out0,
    float* __restrict__ ws){
  unsigned short* hhp = (unsigned short*)(ws + OFF_HHP);
  unsigned short* hlp = (unsigned short*)(ws + OFF_HLP);
  unsigned short* oh  = (unsigned short*)(ws + OFF_OH);
  unsigned short* ol  = (unsigned short*)(ws + OFF_OL);
  int which = blockIdx.x >> 5;
  int idx = (blockIdx.x & 31)*256 + threadIdx.x;
  if (which==0){ ((float4*)(ws+OFF_TC))[idx] = ((const float4*)tc0)[idx]; return; }
  if (which==1){ ((float4*)(ws+OFF_XC))[idx] = ((const float4*)xc0)[idx]; return; }
  const float* s = which==2? th0 : which==3? xh0 : out0;
  float4 v = ((const float4*)s)[idx];
  ushort4 h, l;
  split2(v.x,h.x,l.x); split2(v.y,h.y,l.y); split2(v.z,h.z,l.z); split2(v.w,h.w,l.w);
  if (which==4){
    *(ushort4*)(oh + (size_t)idx*4) = h; *(ushort4*)(ol + (size_t)idx*4) = l;
  } else {
    size_t base = (size_t)(which-2)*BB*HH + (size_t)idx*4;
    *(ushort4*)(hhp+base) = h; *(ushort4*)(hlp+base) = l;
  }
}

// ---- per step: MFMA gate GEMM. grid 256 = bn(32) x ks(8), 256 thr ----
__global__ __launch_bounds__(256) void k_gemm(const unsigned short* __restrict__ wt_hi,
    const unsigned short* __restrict__ wt_lo, const unsigned short* __restrict__ eh,
    const unsigned short* __restrict__ el, const unsigned short* __restrict__ oh,
    const unsigned short* __restrict__ ol, const unsigned short* __restrict__ hhp,
    const unsigned short* __restrict__ hlp, float* __restrict__ gpart, int t){
  int tid = threadIdx.x, lane = tid & 63, wave = tid >> 6;
  int bn = blockIdx.x & 31, ks = blockIdx.x >> 5;
  int lm = lane & 15, lk = (lane >> 4) << 3;
  f32x4 acc[2][4];
  #pragma unroll
  for (int i=0;i<2;i++)
    #pragma unroll
    for (int j=0;j<4;j++) acc[i][j] = (f32x4){0.f,0.f,0.f,0.f};
  size_t ebase[2], obase[2], hbase[2];
  #pragma unroll
  for (int i=0;i<2;i++){
    int r = (wave*2 + i)*16 + lm;
    int b = r & 63, br = r >> 6;
    ebase[i] = ((size_t)t*BB + b)*HH;
    obase[i] = (size_t)b*HH;
    hbase[i] = ((size_t)br*BB + b)*HH;
  }
  size_t wb[4];
  #pragma unroll
  for (int j=0;j<4;j++) wb[j] = (size_t)(bn*64 + j*16 + lm)*1536;
  #pragma unroll
  for (int c=0;c<6;c++){
    int kc = ks*192 + c*32;
    int sec = kc >> 9;
    int kk = (kc & 511) + lk;
    const unsigned short* ph = sec==0? eh : sec==1? oh : hhp;
    const unsigned short* pl = sec==0? el : sec==1? ol : hlp;
    bf16x8 ah[2], al[2], wh_[4], wl_[4];
    #pragma unroll
    for (int i=0;i<2;i++){
      size_t off = (sec==0? ebase[i] : sec==1? obase[i] : hbase[i]) + kk;
      ah[i] = *(const bf16x8*)(ph + off);
      al[i] = *(const bf16x8*)(pl + off);
    }
    int kw = kc + lk;
    #pragma unroll
    for (int j=0;j<4;j++){
      wh_[j] = *(const bf16x8*)(wt_hi + wb[j] + kw);
      wl_[j] = *(const bf16x8*)(wt_lo + wb[j] + kw);
    }
    #pragma unroll
    for (int i=0;i<2;i++)
      #pragma unroll
      for (int j=0;j<4;j++){
        acc[i][j] = __builtin_amdgcn_mfma_f32_16x16x32_bf16(ah[i], wh_[j], acc[i][j], 0,0,0);
        acc[i][j] = __builtin_amdgcn_mfma_f32_16x16x32_bf16(ah[i], wl_[j], acc[i][j], 0,0,0);
        acc[i][j] = __builtin_amdgcn_mfma_f32_16x16x32_bf16(al[i], wh_[j], acc[i][j], 0,0,0);
      }
  }
  int lr4 = (lane >> 4) * 4;
  #pragma unroll
  for (int i=0;i<2;i++){
    int m0 = (wave*2+i)*16;
    #pragma unroll
    for (int j=0;j<4;j++){
      int col = bn*64 + j*16 + lm;
      #pragma unroll
      for (int q=0;q<4;q++){
        int row = m0 + lr4 + q;
        gpart[((size_t)ks*128 + row)*H4 + col] = acc[i][j][q];
      }
    }
  }
}

// ---- per step: 8-way partial reduce + LSTM pointwise. grid 128 x 256 ----
__global__ __launch_bounds__(256) void k_lstm(float* __restrict__ ws,
    const float* __restrict__ bias, int rs){
  int gid = blockIdx.x*256 + threadIdx.x;
  int b = gid >> 9, j = gid & 511;
  int wsl = rs ^ 1;
  const float* gp = ws + OFF_G;
  unsigned short* hhp = (unsigned short*)(ws + OFF_HHP);
  unsigned short* hlp = (unsigned short*)(ws + OFF_HLP);
  #pragma unroll
  for (int br=0;br<2;br++){
    float g0=0.f,g1=0.f,g2=0.f,g3=0.f;
    #pragma unroll
    for (int ks=0;ks<8;ks++){
      size_t base = ((size_t)ks*128 + br*64 + b)*H4 + j;
      g0 += gp[base]; g1 += gp[base+512]; g2 += gp[base+1024]; g3 += gp[base+1536];
    }
    g0 += bias[j]; g1 += bias[512+j]; g2 += bias[1024+j]; g3 += bias[1536+j];
    size_t hoff = (br? OFF_XH : OFF_TH), coff = (br? OFF_XC : OFF_TC);
    float cold = ws[coff + (size_t)rs*BB*HH + (size_t)b*HH + j];
    float cn = sigm(g1)*cold + sigm(g0)*tanhf(g2);
    float hn = sigm(g3)*tanhf(cn);
    ws[coff + (size_t)wsl*BB*HH + (size_t)b*HH + j] = cn;
    ws[hoff + (size_t)wsl*BB*HH + (size_t)b*HH + j] = hn;
    unsigned short h_, l_;
    split2(hn, h_, l_);
    hhp[(size_t)(br*64+b)*HH + j] = h_;
    hlp[(size_t)(br*64+b)*HH + j] = l_;
  }
}

// ---- per step: tgt = h @ W_in, full K, FINAL. grid 64 = cn(8) x mt(8) ----
__global__ __launch_bounds__(256) void k_tgtB(const unsigned short* __restrict__ wit_hi,
    const unsigned short* __restrict__ wit_lo, const unsigned short* __restrict__ hhp,
    const unsigned short* __restrict__ hlp, float* __restrict__ tgt){
  int tid = threadIdx.x, lane = tid & 63, wave = tid >> 6;
  int cn = blockIdx.x & 7, mt = blockIdx.x >> 3;
  int lm = lane & 15, lk = (lane >> 4) << 3;
  f32x4 acc = (f32x4){0.f,0.f,0.f,0.f};
  size_t abase = (size_t)(mt*16 + lm)*HH;
  size_t wb = (size_t)(cn*64 + wave*16 + lm)*HH;
  #pragma unroll
  for (int c=0;c<16;c++){
    int kc = c*32 + lk;
    bf16x8 ah  = *(const bf16x8*)(hhp + abase + kc);
    bf16x8 al  = *(const bf16x8*)(hlp + abase + kc);
    bf16x8 wh_ = *(const bf16x8*)(wit_hi + wb + kc);
    bf16x8 wl_ = *(const bf16x8*)(wit_lo + wb + kc);
    acc = __builtin_amdgcn_mfma_f32_16x16x32_bf16(ah, wh_, acc, 0,0,0);
    acc = __builtin_amdgcn_mfma_f32_16x16x32_bf16(ah, wl_, acc, 0,0,0);
    acc = __builtin_amdgcn_mfma_f32_16x16x32_bf16(al, wh_, acc, 0,0,0);
  }
  int lr4 = (lane >> 4) * 4;
  int col = cn*64 + wave*16 + lm;
  #pragma unroll
  for (int q=0;q<4;q++)
    tgt[(size_t)(mt*16 + lr4 + q)*HH + col] = acc[q];
}

// ---- per step: FLASH-FUSED attention partial (single ctx read, online softmax) ----
__global__ __launch_bounds__(512, 8) void k_attn(const float* __restrict__ tree_ctx,
    const float* __restrict__ text_ctx, const unsigned short* __restrict__ ctx16,
    float* __restrict__ ws, int use16){
  int blk = blockIdx.x;
  int sh = blk & 7, b = (blk>>3) & 63, branch = blk >> 9;
  int tid = threadIdx.x, lane = tid & 63, wave = tid >> 6;
  __shared__ float tgt_s[512];
  __shared__ float accs[8][512];
  __shared__ float wm_s[8], wl_s[8];
  int row128 = branch*64 + b;
  if (tid < 128)
    ((float4*)tgt_s)[tid] = ((const float4*)(ws + OFF_TGTP + (size_t)row128*HH))[tid];
  __syncthreads();
  const size_t CH = (size_t)BB*SS*HH;
  const float* ctxf = (branch? text_ctx : tree_ctx) + ((size_t)b*SS + sh*50)*HH;
  const unsigned short* c16 = ctx16 + (branch? CH:0) + ((size_t)b*SS + sh*50)*HH;
  float4 ta = *(const float4*)&tgt_s[lane*8];
  float4 tb = *(const float4*)&tgt_s[lane*8+4];
  float m = -INFINITY, l = 0.f;
  float a[8] = {0,0,0,0,0,0,0,0};
  if (use16){
    for (int r = wave; r < 50; r += 8){
      uint4 u = *(const uint4*)(c16 + (size_t)r*HH + lane*8);
      float v0=blo(u.x), v1=bhi(u.x), v2=blo(u.y), v3=bhi(u.y);
      float v4=blo(u.z), v5=bhi(u.z), v6=blo(u.w), v7=bhi(u.w);
      float p = v0*ta.x + v1*ta.y + v2*ta.z + v3*ta.w
              + v4*tb.x + v5*tb.y + v6*tb.z + v7*tb.w;
      #pragma unroll
      for (int off=32; off; off>>=1) p += __shfl_xor(p, off, 64);
      float mn = fmaxf(m, p);
      float scale = __expf(m - mn);
      float e = __expf(p - mn);
      l = l*scale + e;
      a[0] = a[0]*scale + e*v0; a[1] = a[1]*scale + e*v1;
      a[2] = a[2]*scale + e*v2; a[3] = a[3]*scale + e*v3;
      a[4] = a[4]*scale + e*v4; a[5] = a[5]*scale + e*v5;
      a[6] = a[6]*scale + e*v6; a[7] = a[7]*scale + e*v7;
      m = mn;
    }
  } else {
    for (int r = wave; r < 50; r += 8){
      const float* crow = ctxf + (size_t)r*HH + lane*8;
      float4 ca = *(const float4*)crow;
      float4 cb = *(const float4*)(crow+4);
      float p = ca.x*ta.x + ca.y*ta.y + ca.z*ta.z + ca.w*ta.w
              + cb.x*tb.x + cb.y*tb.y + cb.z*tb.z + cb.w*tb.w;
      #pragma unroll
      for (int off=32; off; off>>=1) p += __shfl_xor(p, off, 64);
      float mn = fmaxf(m, p);
      float scale = __expf(m - mn);
      float e = __expf(p - mn);
      l = l*scale + e;
      a[0] = a[0]*scale + e*ca.x; a[1] = a[1]*scale + e*ca.y;
      a[2] = a[2]*scale + e*ca.z; a[3] = a[3]*scale + e*ca.w;
      a[4] = a[4]*scale + e*cb.x; a[5] = a[5]*scale + e*cb.y;
      a[6] = a[6]*scale + e*cb.z; a[7] = a[7]*scale + e*cb.w;
      m = mn;
    }
  }
  if (lane==0){ wm_s[wave] = m; wl_s[wave] = l; }
  #pragma unroll
  for (int j=0;j<8;j++) accs[wave][lane*8+j] = a[j];
  __syncthreads();
  float M = wm_s[0];
  #pragma unroll
  for (int w8=1;w8<8;w8++) M = fmaxf(M, wm_s[w8]);
  float s = 0.f;
  #pragma unroll
  for (int w8=0;w8<8;w8++) s += accs[w8][tid] * __expf(wm_s[w8] - M);
  int pidx = (branch*64 + b)*8 + sh;
  ws[OFF_PACC + (size_t)pidx*HH + tid] = s;
  if (tid==0){
    float L = 0.f;
    #pragma unroll
    for (int w8=0;w8<8;w8++) L += wl_s[w8]*__expf(wm_s[w8] - M);
    ws[OFF_PML + (size_t)pidx*2]   = M;
    ws[OFF_PML + (size_t)pidx*2+1] = L;
  }
}

// ---- per step: merge attn partials -> comb hi/lo bf16 [64][1024]. grid 64 ----
__global__ __launch_bounds__(256) void k_outA(float* __restrict__ ws){
  __shared__ float ce_s[2][8];
  int b = blockIdx.x, tid = threadIdx.x;
  if (tid < 2){
    int p0 = (tid*64 + b)*8;
    float mv[8], lv[8];
    float M = -INFINITY;
    #pragma unroll
    for (int i=0;i<8;i++){
      mv[i] = ws[OFF_PML + (size_t)(p0+i)*2];
      lv[i] = ws[OFF_PML + (size_t)(p0+i)*2+1];
      M = fmaxf(M, mv[i]);
    }
    float L = 0.f, ev[8];
    #pragma unroll
    for (int i=0;i<8;i++){ ev[i] = __expf(mv[i]-M); L += lv[i]*ev[i]; }
    #pragma unroll
    for (int i=0;i<8;i++) ce_s[tid][i] = ev[i]/L;
  }
  __syncthreads();
  int h = tid*4;
  int sec = h >> 9, hs = h & 511;
  int p0 = (sec*64 + b)*8;
  float4 v = {0,0,0,0};
  #pragma unroll
  for (int p=0;p<8;p++){
    float4 a = *(const float4*)(ws + OFF_PACC + (size_t)(p0+p)*HH + hs);
    float cw = ce_s[sec][p];
    v.x += a.x*cw; v.y += a.y*cw; v.z += a.z*cw; v.w += a.w*cw;
  }
  ushort4 hv, lv;
  split2(v.x,hv.x,lv.x); split2(v.y,hv.y,lv.y); split2(v.z,hv.z,lv.z); split2(v.w,hv.w,lv.w);
  unsigned short* ch = (unsigned short*)(ws + OFF_COMBH);
  unsigned short* cl = (unsigned short*)(ws + OFF_COMBL);
  *(ushort4*)(ch + (size_t)b*1024 + h) = hv;
  *(ushort4*)(cl + (size_t)b*1024 + h) = lv;
}

// ---- per step (fast): fused out GEMM + tanh + store + O planes.
// grid 128 = nt(32) x mt(4); 4 waves split K=2048 4-way, LDS reduce, epilogue.
__global__ __launch_bounds__(256) void k_outBF(const unsigned short* __restrict__ wot_hi,
    const unsigned short* __restrict__ wot_lo, const unsigned short* __restrict__ combh,
    const unsigned short* __restrict__ combl, const unsigned short* __restrict__ hhp,
    const unsigned short* __restrict__ hlp, float* __restrict__ dout,
    unsigned short* __restrict__ oh, unsigned short* __restrict__ ol, int t){
  __shared__ float accs[4][16][17];
  int tid = threadIdx.x, lane = tid & 63, wave = tid >> 6;
  int nt = blockIdx.x & 31, mt = blockIdx.x >> 5;
  int lm = lane & 15, lk = (lane >> 4) << 3;
  f32x4 acc = (f32x4){0.f,0.f,0.f,0.f};
  int b = mt*16 + lm;
  int col = nt*16 + lm;
  size_t wb = (size_t)col*H4 + (size_t)wave*512;
  const unsigned short *pa_h, *pa_l;
  size_t abase;
  if (wave < 2){ pa_h = combh; pa_l = combl; abase = (size_t)b*1024 + (size_t)wave*512; }
  else         { pa_h = hhp;   pa_l = hlp;   abase = ((size_t)(wave-2)*64 + b)*HH; }
  #pragma unroll
  for (int c=0;c<16;c++){
    int kk = c*32 + lk;
    bf16x8 ah  = *(const bf16x8*)(pa_h + abase + kk);
    bf16x8 al  = *(const bf16x8*)(pa_l + abase + kk);
    bf16x8 wh_ = *(const bf16x8*)(wot_hi + wb + kk);
    bf16x8 wl_ = *(const bf16x8*)(wot_lo + wb + kk);
    acc = __builtin_amdgcn_mfma_f32_16x16x32_bf16(ah, wh_, acc, 0,0,0);
    acc = __builtin_amdgcn_mfma_f32_16x16x32_bf16(ah, wl_, acc, 0,0,0);
    acc = __builtin_amdgcn_mfma_f32_16x16x32_bf16(al, wh_, acc, 0,0,0);
  }
  int lr4 = (lane >> 4) * 4;
  #pragma unroll
  for (int q=0;q<4;q++) accs[wave][lr4+q][lm] = acc[q];
  __syncthreads();
  int row = tid >> 4, colL = tid & 15;
  float s = accs[0][row][colL] + accs[1][row][colL]
          + accs[2][row][colL] + accs[3][row][colL];
  float v = tanhf(s);
  int bb = mt*16 + row, cc = nt*16 + colL;
  dout[((size_t)bb*TT + t)*HH + cc] = v;
  unsigned short h_, l_;
  split2(v, h_, l_);
  oh[(size_t)bb*HH + cc] = h_;
  ol[(size_t)bb*HH + cc] = l_;
}

// ======== fallback-path kernels (small ws) ========
__global__ __launch_bounds__(256) void k_outB(const float* __restrict__ W_out,
    float* __restrict__ ws, int wsl){
  __shared__ float comb_s[16][256];
  __shared__ float ce_s[16][8];
  int tid = threadIdx.x, lane = tid & 63, wave = tid >> 6;
  int blk = blockIdx.x;
  int ct = blk & 7, bg = (blk>>3)&3, ks = blk>>5;
  int b0 = bg*16;
  int k0 = ks*256;
  int sec = ks >> 1;
  int kk0 = (ks & 1)*256;
  int c = ct*64 + lane;
  if (sec < 2){
    if (tid < 16){
      int b = b0 + tid;
      int p0 = (sec*64 + b)*8;
      float mv[8], lv[8];
      float M = -INFINITY;
      #pragma unroll
      for (int i=0;i<8;i++){
        mv[i] = ws[OFF_PML + (size_t)(p0+i)*2];
        lv[i] = ws[OFF_PML + (size_t)(p0+i)*2+1];
        M = fmaxf(M, mv[i]);
      }
      float L = 0.f, ev[8];
      #pragma unroll
      for (int i=0;i<8;i++){ ev[i] = __expf(mv[i]-M); L += lv[i]*ev[i]; }
      #pragma unroll
      for (int i=0;i<8;i++) ce_s[tid][i] = ev[i]/L;
    }
    __syncthreads();
  }
  #pragma unroll
  for (int i=0;i<4;i++){
    int flat = tid + i*256;
    int row = flat >> 6;
    int q   = flat & 63;
    int b = b0 + row;
    int h = kk0 + q*4;
    float4 v;
    if (sec < 2){
      int p0 = (sec*64 + b)*8;
      v.x = 0.f; v.y = 0.f; v.z = 0.f; v.w = 0.f;
      #pragma unroll
      for (int p=0;p<8;p++){
        float4 a = *(const float4*)(ws + OFF_PACC + (size_t)(p0+p)*HH + h);
        float cw = ce_s[row][p];
        v.x += a.x*cw; v.y += a.y*cw; v.z += a.z*cw; v.w += a.w*cw;
      }
    } else {
      size_t hoff = (sec==2 ? OFF_TH : OFF_XH) + (size_t)wsl*BB*HH;
      v = *(const float4*)(ws + hoff + (size_t)b*HH + h);
    }
    *(float4*)&comb_s[row][q*4] = v;
  }
  __syncthreads();
  float acc[4] = {0,0,0,0};
  #pragma unroll 4
  for (int k=0;k<256;k++){
    float wv = W_out[(size_t)(k0+k)*HH + c];
    #pragma unroll
    for (int i=0;i<4;i++) acc[i] += comb_s[wave*4+i][k]*wv;
  }
  #pragma unroll
  for (int i=0;i<4;i++){
    int b = b0 + wave*4 + i;
    ws[OFF_PART + ((size_t)ks*BB + b)*HH + c] = acc[i];
  }
}

__global__ __launch_bounds__(256) void k_outC(float* __restrict__ ws,
    float* __restrict__ dout, int t){
  int gid = blockIdx.x*256 + threadIdx.x;
  int b = gid >> 7, cq = gid & 127;
  int c0 = cq*4;
  float4 s = {0,0,0,0};
  #pragma unroll
  for (int ks=0;ks<8;ks++){
    float4 p = *(const float4*)(ws + OFF_PART + ((size_t)ks*BB + b)*HH + c0);
    s.x += p.x; s.y += p.y; s.z += p.z; s.w += p.w;
  }
  float4 o;
  o.x = tanhf(s.x); o.y = tanhf(s.y); o.z = tanhf(s.z); o.w = tanhf(s.w);
  *(float4*)(dout + ((size_t)b*TT + t)*HH + c0) = o;
  ushort4 h, l;
  split2(o.x,h.x,l.x); split2(o.y,h.y,l.y); split2(o.z,h.z,l.z); split2(o.w,h.w,l.w);
  unsigned short* oh = (unsigned short*)(ws + OFF_OH);
  unsigned short* ol = (unsigned short*)(ws + OFF_OL);
  *(ushort4*)(oh + (size_t)b*HH + c0) = h;
  *(ushort4*)(ol + (size_t)b*HH + c0) = l;
}

extern "C" void kernel_launch(void* const* d_in, const int* in_sizes, int n_in,
                              void* d_out, int out_size, void* d_ws, size_t ws_size,
                              hipStream_t stream){
  const int*   inp   = (const int*)  d_in[0];
  const float* emb0  = (const float*)d_in[1];
  const float* out0  = (const float*)d_in[2];
  const float* th0   = (const float*)d_in[3];
  const float* tc0   = (const float*)d_in[4];
  const float* trctx = (const float*)d_in[5];
  const float* xh0   = (const float*)d_in[6];
  const float* xc0   = (const float*)d_in[7];
  const float* txctx = (const float*)d_in[8];
  const float* wemb  = (const float*)d_in[9];
  const float* Wx    = (const float*)d_in[10];
  const float* Wh    = (const float*)d_in[11];
  const float* bias  = (const float*)d_in[12];
  const float* W_in  = (const float*)d_in[13];
  const float* W_out = (const float*)d_in[14];
  float* ws  = (float*)d_ws;
  float* out = (float*)d_out;
  unsigned short* wt_hi  = (unsigned short*)(ws + OFF_WT_HI);
  unsigned short* wt_lo  = (unsigned short*)(ws + OFF_WT_LO);
  unsigned short* wit_hi = (unsigned short*)(ws + OFF_WIT_HI);
  unsigned short* wit_lo = (unsigned short*)(ws + OFF_WIT_LO);
  unsigned short* wot_hi = (unsigned short*)(ws + OFF_WOT_HI);
  unsigned short* wot_lo = (unsigned short*)(ws + OFF_WOT_LO);
  unsigned short* combh  = (unsigned short*)(ws + OFF_COMBH);
  unsigned short* combl  = (unsigned short*)(ws + OFF_COMBL);
  unsigned short* eh  = (unsigned short*)(ws + OFF_EH);
  unsigned short* el  = (unsigned short*)(ws + OFF_EL);
  unsigned short* oh  = (unsigned short*)(ws + OFF_OH);
  unsigned short* ol  = (unsigned short*)(ws + OFF_OL);
  unsigned short* hhp = (unsigned short*)(ws + OFF_HHP);
  unsigned short* hlp = (unsigned short*)(ws + OFF_HLP);
  unsigned short* ctx16 = (unsigned short*)(ws + OFF_CTX16);
  float* gpart = ws + OFF_G;
  float* tgt   = ws + OFF_TGTP;
  int use16 = (ws_size >= (size_t)WS_NEED_F  * 4u) ? 1 : 0;
  int fast  = (ws_size >= (size_t)WS_NEED2_F * 4u) ? 1 : 0;
  const size_t CH = (size_t)BB*SS*HH;

  hipLaunchKernelGGL(k_wprep,  dim3(768),   dim3(256), 0, stream, Wx, Wh, wt_hi, wt_lo);
  hipLaunchKernelGGL(k_wiprep, dim3(64),    dim3(256), 0, stream, W_in, wit_hi, wit_lo);
  if (fast)
    hipLaunchKernelGGL(k_woprep, dim3(256), dim3(256), 0, stream, W_out, wot_hi, wot_lo);
  if (use16){
    hipLaunchKernelGGL(k_ctx16, dim3(6400), dim3(256), 0, stream, trctx, ctx16);
    hipLaunchKernelGGL(k_ctx16, dim3(6400), dim3(256), 0, stream, txctx, ctx16 + CH);
  }
  hipLaunchKernelGGL(k_prep,   dim3(TT*BB), dim3(128), 0, stream, inp, emb0, wemb, eh, el);
  hipLaunchKernelGGL(k_init,   dim3(160),   dim3(256), 0, stream, th0, tc0, xh0, xc0, out0, ws);
  for (int t=0; t<TT; t++){
    int rs = t & 1, wsl = rs ^ 1;
    hipLaunchKernelGGL(k_gemm, dim3(256),  dim3(256), 0, stream,
                       wt_hi, wt_lo, eh, el, oh, ol, hhp, hlp, gpart, t);
    hipLaunchKernelGGL(k_lstm, dim3(128),  dim3(256), 0, stream, ws, bias, rs);
    hipLaunchKernelGGL(k_tgtB, dim3(64),   dim3(256), 0, stream, wit_hi, wit_lo, hhp, hlp, tgt);
    hipLaunchKernelGGL(k_attn, dim3(1024), dim3(512), 0, stream, trctx, txctx, ctx16, ws, use16);
    if (fast){
      hipLaunchKernelGGL(k_outA,  dim3(64),  dim3(256), 0, stream, ws);
      hipLaunchKernelGGL(k_outBF, dim3(128), dim3(256), 0, stream,
                         wot_hi, wot_lo, combh, combl, hhp, hlp, out, oh, ol, t);
    } else {
      hipLaunchKernelGGL(k_outB, dim3(256), dim3(256), 0, stream, W_out, ws, wsl);
      hipLaunchKernelGGL(k_outC, dim3(32),  dim3(256), 0, stream, ws, out, t);
    }
  }
}